// Round 1
// baseline (40578.625 us; speedup 1.0000x reference)
//
#include <hip/hip_runtime.h>
#include <hip/hip_fp16.h>
#include <stdint.h>

#define TT 2048
#define BB 16
#define DD 1024
static const size_t H0OFF = 33554432; // 2048*16*1024 floats (start of h section in d_out)

typedef _Float16 f16;
typedef _Float16 f16x2 __attribute__((ext_vector_type(2)));
typedef _Float16 f16x8 __attribute__((ext_vector_type(8)));
typedef float f32x4 __attribute__((ext_vector_type(4)));

// ---------------- threefry + normal (replicates jax.random.normal(key(1),(1024,),f32)) ----
__device__ __forceinline__ float erfinv_xla(float x) {
  // Mike Giles' single-precision erfinv == XLA ErfInv32
  float w = -log1pf(-x * x);
  float p;
  if (w < 5.0f) {
    w -= 2.5f;
    p = 2.81022636e-08f;
    p = fmaf(p, w, 3.43273939e-07f);
    p = fmaf(p, w, -3.5233877e-06f);
    p = fmaf(p, w, -4.39150654e-06f);
    p = fmaf(p, w, 0.00021858087f);
    p = fmaf(p, w, -0.00125372503f);
    p = fmaf(p, w, -0.00417768164f);
    p = fmaf(p, w, 0.246640727f);
    p = fmaf(p, w, 1.50140941f);
  } else {
    w = sqrtf(w) - 3.0f;
    p = -0.000200214257f;
    p = fmaf(p, w, 0.000100950558f);
    p = fmaf(p, w, 0.00134934322f);
    p = fmaf(p, w, -0.00367342844f);
    p = fmaf(p, w, 0.00573950773f);
    p = fmaf(p, w, -0.0076224613f);
    p = fmaf(p, w, 0.00943887047f);
    p = fmaf(p, w, 1.00167406f);
    p = fmaf(p, w, 2.83297682f);
  }
  return p * x;
}

__device__ __forceinline__ float bits_to_normal(unsigned bits) {
  unsigned fb = (bits >> 9) | 0x3f800000u;
  float f = __uint_as_float(fb) - 1.0f;          // [0,1)
  const float lo = -0.99999994f;                 // nextafterf(-1,0)
  float u = f * 2.0f + lo;                       // (maxval-minval) rounds to 2.0f in fp32
  u = fmaxf(lo, u);
  return __uint_as_float(0x3fb504f3u) * erfinv_xla(u); // sqrt(2) fp32
}

#define TF_ROUND(r) { x0 += x1; x1 = (x1 << r) | (x1 >> (32 - r)); x1 ^= x0; }

__global__ void k_u0(float* t0, float* u) {
  __shared__ float red[512];
  int i = threadIdx.x; // 512 threads
  unsigned ks0 = 0u, ks1 = 1u, ks2 = 0x1BD11BDAu ^ 0u ^ 1u;
  unsigned x0 = (unsigned)i + ks0;
  unsigned x1 = (unsigned)(i + 512) + ks1;
  TF_ROUND(13) TF_ROUND(15) TF_ROUND(26) TF_ROUND(6)
  x0 += ks1; x1 += ks2 + 1u;
  TF_ROUND(17) TF_ROUND(29) TF_ROUND(16) TF_ROUND(24)
  x0 += ks2; x1 += ks0 + 2u;
  TF_ROUND(13) TF_ROUND(15) TF_ROUND(26) TF_ROUND(6)
  x0 += ks0; x1 += ks1 + 3u;
  TF_ROUND(17) TF_ROUND(29) TF_ROUND(16) TF_ROUND(24)
  x0 += ks1; x1 += ks2 + 4u;
  TF_ROUND(13) TF_ROUND(15) TF_ROUND(26) TF_ROUND(6)
  x0 += ks2; x1 += ks0 + 5u;
  float z0 = bits_to_normal(x0);
  float z1 = bits_to_normal(x1);
  t0[i] = z0; t0[i + 512] = z1;
  red[i] = z0 * z0 + z1 * z1;
  __syncthreads();
  for (int s = 256; s > 0; s >>= 1) { if (i < s) red[i] += red[i + s]; __syncthreads(); }
  float inv = 1.0f / sqrtf(red[0]);  // first normalize: no eps (u/||u||)
  u[i] = t0[i] * inv; u[i + 512] = t0[i + 512] * inv;
}

// ---------------- power iteration helpers ----------------
__global__ void k_mvT(const float* __restrict__ W, const float* __restrict__ u,
                      float* __restrict__ out) { // out[j] = sum_i W[i,j]*u[i]
  int j = blockIdx.x * 256 + threadIdx.x;
  float acc = 0.f;
  for (int i = 0; i < DD; ++i) acc = fmaf(W[(size_t)i * DD + j], u[i], acc);
  out[j] = acc;
}

__global__ void k_mv(const float* __restrict__ W, const float* __restrict__ v,
                     float* __restrict__ out) { // out[i] = sum_j W[i,j]*v[j]
  int gtid = blockIdx.x * 256 + threadIdx.x;
  int wave = gtid >> 6, lane = threadIdx.x & 63;
  for (int rr = 0; rr < 16; ++rr) {
    int row = wave * 16 + rr;
    float acc = 0.f;
    for (int c = 0; c < 16; ++c) {
      int col = c * 64 + lane;
      acc = fmaf(W[(size_t)row * DD + col], v[col], acc);
    }
    for (int off = 32; off > 0; off >>= 1) acc += __shfl_down(acc, off, 64);
    if (lane == 0) out[row] = acc;
  }
}

__global__ void k_norm(const float* __restrict__ src, float* __restrict__ dst, float eps) {
  __shared__ float red[1024];
  int i = threadIdx.x;
  float xv = src[i];
  red[i] = xv * xv;
  __syncthreads();
  for (int s = 512; s > 0; s >>= 1) { if (i < s) red[i] += red[i + s]; __syncthreads(); }
  float inv = 1.0f / (sqrtf(red[0]) + eps);
  dst[i] = src[i] * inv;
}

__global__ void k_sigma(const float* __restrict__ u, const float* __restrict__ wv,
                        float* __restrict__ scale) {
  __shared__ float red[1024];
  int i = threadIdx.x;
  red[i] = u[i] * wv[i];
  __syncthreads();
  for (int s = 512; s > 0; s >>= 1) { if (i < s) red[i] += red[i + s]; __syncthreads(); }
  if (i == 0) scale[0] = 0.99f / (fabsf(red[0]) + 1e-8f);
}

__global__ void k_castW(const float* __restrict__ Wx, const float* __restrict__ Wd,
                        const float* __restrict__ Wh, const float* __restrict__ scale,
                        f16* __restrict__ WxH, f16* __restrict__ WdH, f16* __restrict__ WhH) {
  int i = blockIdx.x * 256 + threadIdx.x;
  float s = scale[0];
  WxH[i] = (f16)Wx[i];
  WdH[i] = (f16)Wd[i];
  WhH[i] = (f16)(Wh[i] * s);
}

// ---------------- batched GEMM: C[m,e] = sum_d X[m,d]*Wt[e,d] + bias[e] ----------------
__global__ __launch_bounds__(256) void k_gemm(const float* __restrict__ X,
                                              const f16* __restrict__ Wt,
                                              const float* __restrict__ bias,
                                              float* __restrict__ Cout) {
  __shared__ __align__(16) f16 Ah[128 * 64];
  __shared__ __align__(16) f16 Bh[128 * 64];
  int m0 = blockIdx.x * 128, n0 = blockIdx.y * 128;
  int tid = threadIdx.x, lane = tid & 63, w = tid >> 6;
  int wm = w & 1, wn = w >> 1;
  int srow = tid >> 3, scol = (tid & 7) * 8;
  f32x4 acc[4][4];
#pragma unroll
  for (int i = 0; i < 4; ++i)
#pragma unroll
    for (int j = 0; j < 4; ++j) acc[i][j] = (f32x4){0.f, 0.f, 0.f, 0.f};

  for (int kt = 0; kt < 16; ++kt) {
    int k0 = kt * 64;
#pragma unroll
    for (int c = 0; c < 4; ++c) {
      int row = c * 32 + srow;
      const float4* sa = (const float4*)(X + (size_t)(m0 + row) * DD + k0 + scol);
      float4 a0 = sa[0], a1 = sa[1];
      f16x8 hv;
      hv[0] = (f16)a0.x; hv[1] = (f16)a0.y; hv[2] = (f16)a0.z; hv[3] = (f16)a0.w;
      hv[4] = (f16)a1.x; hv[5] = (f16)a1.y; hv[6] = (f16)a1.z; hv[7] = (f16)a1.w;
      *(f16x8*)&Ah[row * 64 + scol] = hv;
      uint4 qb = *(const uint4*)(Wt + (size_t)(n0 + row) * DD + k0 + scol);
      *(uint4*)&Bh[row * 64 + scol] = qb;
    }
    __syncthreads();
#pragma unroll
    for (int ks = 0; ks < 2; ++ks) {
      f16x8 af[4], bf[4];
#pragma unroll
      for (int i = 0; i < 4; ++i)
        af[i] = *(const f16x8*)&Ah[(wm * 64 + i * 16 + (lane & 15)) * 64 + ks * 32 + (lane >> 4) * 8];
#pragma unroll
      for (int j = 0; j < 4; ++j)
        bf[j] = *(const f16x8*)&Bh[(wn * 64 + j * 16 + (lane & 15)) * 64 + ks * 32 + (lane >> 4) * 8];
#pragma unroll
      for (int i = 0; i < 4; ++i)
#pragma unroll
        for (int j = 0; j < 4; ++j)
          acc[i][j] = __builtin_amdgcn_mfma_f32_16x16x32_f16(af[i], bf[j], acc[i][j], 0, 0, 0);
    }
    __syncthreads();
  }
#pragma unroll
  for (int j = 0; j < 4; ++j) {
    int col = n0 + wn * 64 + j * 16 + (lane & 15);
    float bs = bias[col];
#pragma unroll
    for (int i = 0; i < 4; ++i) {
      int rbase = m0 + wm * 64 + i * 16 + (lane >> 4) * 4;
#pragma unroll
      for (int r = 0; r < 4; ++r)
        Cout[(size_t)(rbase + r) * DD + col] = acc[i][j][r] + bs;
    }
  }
}

// ---------------- persistent recurrence ----------------
__device__ __forceinline__ float fdot2f(f16x2 a, f16x2 b, float c) {
#if __has_builtin(__builtin_amdgcn_fdot2)
  return __builtin_amdgcn_fdot2(a, b, c, false);
#else
  return c + (float)a[0] * (float)b[0] + (float)a[1] * (float)b[1];
#endif
}

__global__ __launch_bounds__(256, 1) void k_rec(const float* __restrict__ x,
                                                const float* __restrict__ h0,
                                                const float* __restrict__ b_gate,
                                                const f16* __restrict__ WhH,
                                                f16* hx, unsigned* cnt, float* d_out) {
  int bid = blockIdx.x;
  int batch = (bid & 7) * 2 + ((bid >> 3) & 1);
  int eslice = bid >> 4;           // 0..15
  int e0 = eslice * 64;
  int tid = threadIdx.x, lane = tid & 63, wv = tid >> 6;
  int e = e0 + lane;

  __shared__ __align__(16) uint32_t hsh[512];   // h_t as 512 half2
  __shared__ float partial[4][64];

  // W_h_eff slice into registers: lane owns row e, wave owns d-range [wv*256, wv*256+256)
  f16x2 wreg[128];
  const f16* wrow = WhH + (size_t)e * DD + wv * 256;
#pragma unroll
  for (int k = 0; k < 128; ++k) wreg[k] = *(const f16x2*)(wrow + 2 * k);

  unsigned* mycnt = cnt + batch * 64;   // one cacheline per batch
  f16* hxb0 = hx + (size_t)batch * DD;
  f16* hxb1 = hx + (size_t)(16 * DD) + (size_t)batch * DD;

  float h_own = 0.f, bgv = 0.f;
  float cx_c = 0.f, dr_c = 0.f, xv_c = 0.f;

  if (wv == 0) {
    h_own = h0[(size_t)batch * DD + e];
    bgv = b_gate[e];
    d_out[H0OFF + (size_t)batch * DD + e] = h_own;   // h[0]
    hxb0[e] = (f16)h_own;
    size_t base0 = (size_t)batch * DD + e;           // t = 0
    cx_c = d_out[base0];
    dr_c = d_out[H0OFF + 16384 + base0];
    xv_c = x[base0];
  }
  __threadfence();
  if (tid == 0) {
    atomicAdd(mycnt, 1u);
    while (__hip_atomic_load(mycnt, __ATOMIC_ACQUIRE, __HIP_MEMORY_SCOPE_AGENT) < 16u) {}
  }
  __syncthreads();
  { // stage h0
    uint64_t q = __hip_atomic_load((uint64_t*)hxb0 + tid, __ATOMIC_RELAXED, __HIP_MEMORY_SCOPE_AGENT);
    ((uint64_t*)hsh)[tid] = q;
  }
  __syncthreads();

#pragma unroll 1
  for (int t = 0; t < TT; ++t) {
    float cx_n = 0.f, dr_n = 0.f, xv_n = 0.f;
    if (wv == 0 && t + 1 < TT) {   // prefetch next step's streams (hide HBM latency)
      size_t basen = (size_t)(t + 1) * 16384 + (size_t)batch * DD + e;
      cx_n = d_out[basen];
      dr_n = d_out[H0OFF + 16384 + basen];
      xv_n = x[basen];
    }
    // matvec partial: this wave's 256-d range
    float acc = 0.f;
#pragma unroll
    for (int k4 = 0; k4 < 32; ++k4) {
      uint4 q = *(((const uint4*)hsh) + wv * 32 + k4);
      acc = fdot2f(wreg[k4 * 4 + 0], __builtin_bit_cast(f16x2, q.x), acc);
      acc = fdot2f(wreg[k4 * 4 + 1], __builtin_bit_cast(f16x2, q.y), acc);
      acc = fdot2f(wreg[k4 * 4 + 2], __builtin_bit_cast(f16x2, q.z), acc);
      acc = fdot2f(wreg[k4 * 4 + 3], __builtin_bit_cast(f16x2, q.w), acc);
    }
    partial[wv][lane] = acc;
    __syncthreads();
    if (wv == 0) {
      float hdot = partial[0][lane] + partial[1][lane] + partial[2][lane] + partial[3][lane];
      size_t base = (size_t)t * 16384 + (size_t)batch * DD + e;
      float dlt = 1.f / (1.f + expf(-dr_c));
      float cand = tanhf(cx_c + hdot);
      float hn = (1.f - dlt) * h_own + dlt * cand;
      float z = hn + xv_c + bgv;
      float outv = hn * (z / (1.f + expf(-z)));
      d_out[base] = outv;                       // overwrites cand_x[t] (already consumed)
      d_out[H0OFF + 16384 + base] = hn;         // h[t+1], overwrites delta_raw[t] (consumed)
      f16* dst = ((t + 1) & 1) ? hxb1 : hxb0;
      dst[e] = (f16)hn;
      h_own = hn;
      cx_c = cx_n; dr_c = dr_n; xv_c = xv_n;
    }
    __threadfence();
    if (tid == 0) {
      atomicAdd(mycnt, 1u);
      unsigned target = 16u * (unsigned)(t + 2);
      while (__hip_atomic_load(mycnt, __ATOMIC_ACQUIRE, __HIP_MEMORY_SCOPE_AGENT) < target) {}
    }
    __syncthreads();
    if (t + 1 < TT) {
      f16* src = ((t + 1) & 1) ? hxb1 : hxb0;
      uint64_t q = __hip_atomic_load((uint64_t*)src + tid, __ATOMIC_RELAXED, __HIP_MEMORY_SCOPE_AGENT);
      ((uint64_t*)hsh)[tid] = q;
      __syncthreads();
    }
  }
}

// ---------------- launch ----------------
extern "C" void kernel_launch(void* const* d_in, const int* in_sizes, int n_in,
                              void* d_out_v, int out_size, void* d_ws, size_t ws_size,
                              hipStream_t stream) {
  const float* x  = (const float*)d_in[0];
  const float* h0 = (const float*)d_in[1];
  const float* Wx = (const float*)d_in[2];
  const float* Wh = (const float*)d_in[3];
  const float* Wd = (const float*)d_in[4];
  const float* b  = (const float*)d_in[5];
  const float* bd = (const float*)d_in[6];
  const float* bg = (const float*)d_in[7];
  float* out = (float*)d_out_v;

  char* ws = (char*)d_ws;
  float* u    = (float*)(ws + 0);
  float* v    = (float*)(ws + 4096);
  float* t0   = (float*)(ws + 8192);
  float* sc   = (float*)(ws + 12288);
  unsigned* cnt = (unsigned*)(ws + 16384);
  f16* hx   = (f16*)(ws + 32768);
  f16* WhH  = (f16*)(ws + 98304);
  f16* WxH  = (f16*)(ws + 98304 + 2097152);
  f16* WdH  = (f16*)(ws + 98304 + 2 * 2097152);

  hipMemsetAsync(cnt, 0, 4096, stream);

  k_u0<<<1, 512, 0, stream>>>(t0, u);
  for (int it = 0; it < 3; ++it) {
    k_mvT<<<4, 256, 0, stream>>>(Wh, u, t0);
    k_norm<<<1, 1024, 0, stream>>>(t0, v, 1e-8f);
    k_mv<<<16, 256, 0, stream>>>(Wh, v, t0);
    k_norm<<<1, 1024, 0, stream>>>(t0, u, 1e-8f);
  }
  k_sigma<<<1, 1024, 0, stream>>>(u, t0, sc);
  k_castW<<<4096, 256, 0, stream>>>(Wx, Wd, Wh, sc, WxH, WdH, WhH);

  dim3 gg(256, 8, 1);
  k_gemm<<<gg, 256, 0, stream>>>(x, WxH, b, out);                          // cand_x -> out region
  k_gemm<<<gg, 256, 0, stream>>>(x, WdH, bd, out + H0OFF + 16384);         // delta_raw -> h region (+1 slot)

  k_rec<<<256, 256, 0, stream>>>(x, h0, bg, WhH, hx, cnt, out);
}

// Round 2
// 4262.062 us; speedup vs baseline: 9.5209x; 9.5209x over previous
//
#include <hip/hip_runtime.h>
#include <hip/hip_fp16.h>
#include <stdint.h>

#define TT 2048
#define BB 16
#define DD 1024
static const size_t H0OFF = 33554432; // 2048*16*1024 floats (start of h section in d_out)

typedef _Float16 f16;
typedef _Float16 f16x2 __attribute__((ext_vector_type(2)));
typedef _Float16 f16x8 __attribute__((ext_vector_type(8)));
typedef float f32x4 __attribute__((ext_vector_type(4)));

// ---------------- threefry + normal (replicates jax.random.normal(key(1),(1024,),f32)) ----
__device__ __forceinline__ float erfinv_xla(float x) {
  float w = -log1pf(-x * x);
  float p;
  if (w < 5.0f) {
    w -= 2.5f;
    p = 2.81022636e-08f;
    p = fmaf(p, w, 3.43273939e-07f);
    p = fmaf(p, w, -3.5233877e-06f);
    p = fmaf(p, w, -4.39150654e-06f);
    p = fmaf(p, w, 0.00021858087f);
    p = fmaf(p, w, -0.00125372503f);
    p = fmaf(p, w, -0.00417768164f);
    p = fmaf(p, w, 0.246640727f);
    p = fmaf(p, w, 1.50140941f);
  } else {
    w = sqrtf(w) - 3.0f;
    p = -0.000200214257f;
    p = fmaf(p, w, 0.000100950558f);
    p = fmaf(p, w, 0.00134934322f);
    p = fmaf(p, w, -0.00367342844f);
    p = fmaf(p, w, 0.00573950773f);
    p = fmaf(p, w, -0.0076224613f);
    p = fmaf(p, w, 0.00943887047f);
    p = fmaf(p, w, 1.00167406f);
    p = fmaf(p, w, 2.83297682f);
  }
  return p * x;
}

__device__ __forceinline__ float bits_to_normal(unsigned bits) {
  unsigned fb = (bits >> 9) | 0x3f800000u;
  float f = __uint_as_float(fb) - 1.0f;          // [0,1)
  const float lo = -0.99999994f;                 // nextafterf(-1,0)
  float u = f * 2.0f + lo;
  u = fmaxf(lo, u);
  return __uint_as_float(0x3fb504f3u) * erfinv_xla(u); // sqrt(2) fp32
}

#define TF_ROUND(r) { x0 += x1; x1 = (x1 << r) | (x1 >> (32 - r)); x1 ^= x0; }

__global__ void k_u0(float* t0, float* u) {
  __shared__ float red[512];
  int i = threadIdx.x; // 512 threads
  unsigned ks0 = 0u, ks1 = 1u, ks2 = 0x1BD11BDAu ^ 0u ^ 1u;
  unsigned x0 = (unsigned)i + ks0;
  unsigned x1 = (unsigned)(i + 512) + ks1;
  TF_ROUND(13) TF_ROUND(15) TF_ROUND(26) TF_ROUND(6)
  x0 += ks1; x1 += ks2 + 1u;
  TF_ROUND(17) TF_ROUND(29) TF_ROUND(16) TF_ROUND(24)
  x0 += ks2; x1 += ks0 + 2u;
  TF_ROUND(13) TF_ROUND(15) TF_ROUND(26) TF_ROUND(6)
  x0 += ks0; x1 += ks1 + 3u;
  TF_ROUND(17) TF_ROUND(29) TF_ROUND(16) TF_ROUND(24)
  x0 += ks1; x1 += ks2 + 4u;
  TF_ROUND(13) TF_ROUND(15) TF_ROUND(26) TF_ROUND(6)
  x0 += ks2; x1 += ks0 + 5u;
  float z0 = bits_to_normal(x0);
  float z1 = bits_to_normal(x1);
  t0[i] = z0; t0[i + 512] = z1;
  red[i] = z0 * z0 + z1 * z1;
  __syncthreads();
  for (int s = 256; s > 0; s >>= 1) { if (i < s) red[i] += red[i + s]; __syncthreads(); }
  float inv = 1.0f / sqrtf(red[0]);
  u[i] = t0[i] * inv; u[i + 512] = t0[i + 512] * inv;
}

// ---------------- power iteration helpers ----------------
__global__ void k_mvT(const float* __restrict__ W, const float* __restrict__ u,
                      float* __restrict__ out) { // out[j] = sum_i W[i,j]*u[i]
  int j = blockIdx.x * 256 + threadIdx.x;
  float acc = 0.f;
  for (int i = 0; i < DD; ++i) acc = fmaf(W[(size_t)i * DD + j], u[i], acc);
  out[j] = acc;
}

__global__ void k_mv(const float* __restrict__ W, const float* __restrict__ v,
                     float* __restrict__ out) { // out[i] = sum_j W[i,j]*v[j]
  int gtid = blockIdx.x * 256 + threadIdx.x;
  int wave = gtid >> 6, lane = threadIdx.x & 63;
  for (int rr = 0; rr < 16; ++rr) {
    int row = wave * 16 + rr;
    float acc = 0.f;
    for (int c = 0; c < 16; ++c) {
      int col = c * 64 + lane;
      acc = fmaf(W[(size_t)row * DD + col], v[col], acc);
    }
    for (int off = 32; off > 0; off >>= 1) acc += __shfl_down(acc, off, 64);
    if (lane == 0) out[row] = acc;
  }
}

__global__ void k_norm(const float* __restrict__ src, float* __restrict__ dst, float eps) {
  __shared__ float red[1024];
  int i = threadIdx.x;
  float xv = src[i];
  red[i] = xv * xv;
  __syncthreads();
  for (int s = 512; s > 0; s >>= 1) { if (i < s) red[i] += red[i + s]; __syncthreads(); }
  float inv = 1.0f / (sqrtf(red[0]) + eps);
  dst[i] = src[i] * inv;
}

__global__ void k_sigma(const float* __restrict__ u, const float* __restrict__ wv,
                        float* __restrict__ scale) {
  __shared__ float red[1024];
  int i = threadIdx.x;
  red[i] = u[i] * wv[i];
  __syncthreads();
  for (int s = 512; s > 0; s >>= 1) { if (i < s) red[i] += red[i + s]; __syncthreads(); }
  if (i == 0) scale[0] = 0.99f / (fabsf(red[0]) + 1e-8f);
}

__global__ void k_castWh(const float* __restrict__ Wh, const float* __restrict__ scale,
                         f16* __restrict__ WhH) {
  int i = blockIdx.x * 256 + threadIdx.x;
  float s = scale[0];
  WhH[i] = (f16)(Wh[i] * s);
}

// ---------------- batched GEMM: C[m,e] = sum_d X[m,d]*W[e,d] + bias[e] (W in f32) ------
__global__ __launch_bounds__(256) void k_gemm(const float* __restrict__ X,
                                              const float* __restrict__ Wt,
                                              const float* __restrict__ bias,
                                              float* __restrict__ Cout) {
  __shared__ __align__(16) f16 Ah[128 * 64];
  __shared__ __align__(16) f16 Bh[128 * 64];
  int m0 = blockIdx.x * 128, n0 = blockIdx.y * 128;
  int tid = threadIdx.x, lane = tid & 63, w = tid >> 6;
  int wm = w & 1, wn = w >> 1;
  int srow = tid >> 3, scol = (tid & 7) * 8;
  f32x4 acc[4][4];
#pragma unroll
  for (int i = 0; i < 4; ++i)
#pragma unroll
    for (int j = 0; j < 4; ++j) acc[i][j] = (f32x4){0.f, 0.f, 0.f, 0.f};

  for (int kt = 0; kt < 16; ++kt) {
    int k0 = kt * 64;
#pragma unroll
    for (int c = 0; c < 4; ++c) {
      int row = c * 32 + srow;
      const float4* sa = (const float4*)(X + (size_t)(m0 + row) * DD + k0 + scol);
      float4 a0 = sa[0], a1 = sa[1];
      f16x8 hv;
      hv[0] = (f16)a0.x; hv[1] = (f16)a0.y; hv[2] = (f16)a0.z; hv[3] = (f16)a0.w;
      hv[4] = (f16)a1.x; hv[5] = (f16)a1.y; hv[6] = (f16)a1.z; hv[7] = (f16)a1.w;
      *(f16x8*)&Ah[row * 64 + scol] = hv;
      const float4* sb = (const float4*)(Wt + (size_t)(n0 + row) * DD + k0 + scol);
      float4 b0 = sb[0], b1 = sb[1];
      f16x8 hw;
      hw[0] = (f16)b0.x; hw[1] = (f16)b0.y; hw[2] = (f16)b0.z; hw[3] = (f16)b0.w;
      hw[4] = (f16)b1.x; hw[5] = (f16)b1.y; hw[6] = (f16)b1.z; hw[7] = (f16)b1.w;
      *(f16x8*)&Bh[row * 64 + scol] = hw;
    }
    __syncthreads();
#pragma unroll
    for (int ks = 0; ks < 2; ++ks) {
      f16x8 af[4], bf[4];
#pragma unroll
      for (int i = 0; i < 4; ++i)
        af[i] = *(const f16x8*)&Ah[(wm * 64 + i * 16 + (lane & 15)) * 64 + ks * 32 + (lane >> 4) * 8];
#pragma unroll
      for (int j = 0; j < 4; ++j)
        bf[j] = *(const f16x8*)&Bh[(wn * 64 + j * 16 + (lane & 15)) * 64 + ks * 32 + (lane >> 4) * 8];
#pragma unroll
      for (int i = 0; i < 4; ++i)
#pragma unroll
        for (int j = 0; j < 4; ++j)
          acc[i][j] = __builtin_amdgcn_mfma_f32_16x16x32_f16(af[i], bf[j], acc[i][j], 0, 0, 0);
    }
    __syncthreads();
  }
#pragma unroll
  for (int j = 0; j < 4; ++j) {
    int col = n0 + wn * 64 + j * 16 + (lane & 15);
    float bs = bias[col];
#pragma unroll
    for (int i = 0; i < 4; ++i) {
      int rbase = m0 + wm * 64 + i * 16 + (lane >> 4) * 4;
#pragma unroll
      for (int r = 0; r < 4; ++r)
        Cout[(size_t)(rbase + r) * DD + col] = acc[i][j][r] + bs;
    }
  }
}

// ---------------- persistent recurrence (tagged-data exchange, no fences) ----------------
__device__ __forceinline__ float fdot2f(f16x2 a, f16x2 b, float c) {
#if __has_builtin(__builtin_amdgcn_fdot2)
  return __builtin_amdgcn_fdot2(a, b, c, false);
#else
  return c + (float)a[0] * (float)b[0] + (float)a[1] * (float)b[1];
#endif
}

__device__ __forceinline__ float sigmoid_fast(float v) {
  return 1.0f / (1.0f + __expf(-v));
}
__device__ __forceinline__ float tanh_fast(float v) {
  // overflow-safe: tanh(x) = sign(x) * (1 - t)/(1 + t), t = exp(-2|x|)
  float t = __expf(-2.0f * fabsf(v));
  float r = (1.0f - t) / (1.0f + t);
  return copysignf(r, v);
}

__global__ __launch_bounds__(256, 1) void k_rec(const float* __restrict__ x,
                                                const float* __restrict__ h0,
                                                const float* __restrict__ b_gate,
                                                const f16* __restrict__ WhH,
                                                uint32_t* __restrict__ hx,
                                                float* __restrict__ d_out) {
  int bid = blockIdx.x;
  int batch = bid & 15;          // same-batch blocks land on the same XCD under round-robin
  int eslice = bid >> 4;         // 0..15
  int tid = threadIdx.x, lane = tid & 63, wv = tid >> 6;
  int e0 = eslice * 64;
  int e = e0 + lane;

  __shared__ __align__(16) uint32_t hsh[512];   // h_t as 512 f16x2 words
  __shared__ float partial[4][64];

  // W_h_eff slice: lane owns row e, wave owns d-range [wv*256, wv*256+256)
  f16x2 wreg[128];
  const f16* wrow = WhH + (size_t)e * DD + wv * 256;
#pragma unroll
  for (int k = 0; k < 128; ++k) wreg[k] = *(const f16x2*)(wrow + 2 * k);

  // ---- t = 0 staging: everything comes straight from h0, no cross-block sync ----
  {
    const float* hb = h0 + (size_t)batch * DD + 4 * tid;
    float a0 = hb[0], a1 = hb[1], a2 = hb[2], a3 = hb[3];
    f16x2 p0; p0[0] = (f16)a0; p0[1] = (f16)a1;
    f16x2 p1; p1[0] = (f16)a2; p1[1] = (f16)a3;
    hsh[2 * tid]     = __builtin_bit_cast(uint32_t, p0);
    hsh[2 * tid + 1] = __builtin_bit_cast(uint32_t, p1);
  }
  float h_own = 0.f, bgv = 0.f, cx_c = 0.f, dr_c = 0.f, xv_c = 0.f;
  if (wv == 0) {
    h_own = h0[(size_t)batch * DD + e];
    bgv = b_gate[e];
    d_out[H0OFF + (size_t)batch * DD + e] = h_own;   // h[0]
    size_t base0 = (size_t)batch * DD + e;           // t = 0
    cx_c = d_out[base0];
    dr_c = d_out[H0OFF + 16384 + base0];
    xv_c = x[base0];
  }
  __syncthreads();

#pragma unroll 1
  for (int t = 0; t < TT; ++t) {
    float cx_n = 0.f, dr_n = 0.f, xv_n = 0.f;
    if (wv == 0 && t + 1 < TT) {   // prefetch next step's streams
      size_t basen = (size_t)(t + 1) * 16384 + (size_t)batch * DD + e;
      cx_n = d_out[basen];
      dr_n = d_out[H0OFF + 16384 + basen];
      xv_n = x[basen];
    }
    // matvec partial over this wave's 256-d range (LDS broadcast reads)
    float acc = 0.f;
#pragma unroll
    for (int k4 = 0; k4 < 32; ++k4) {
      uint4 q = *(((const uint4*)hsh) + wv * 32 + k4);
      acc = fdot2f(wreg[k4 * 4 + 0], __builtin_bit_cast(f16x2, q.x), acc);
      acc = fdot2f(wreg[k4 * 4 + 1], __builtin_bit_cast(f16x2, q.y), acc);
      acc = fdot2f(wreg[k4 * 4 + 2], __builtin_bit_cast(f16x2, q.z), acc);
      acc = fdot2f(wreg[k4 * 4 + 3], __builtin_bit_cast(f16x2, q.w), acc);
    }
    partial[wv][lane] = acc;
    __syncthreads();                                  // barrier A

    uint32_t want = (uint32_t)(t + 1);
    uint32_t* slot = hx + (size_t)(want & 15u) * (BB * DD) + (size_t)batch * DD;

    if (wv == 0) {
      float hdot = partial[0][lane] + partial[1][lane] + partial[2][lane] + partial[3][lane];
      float dlt = sigmoid_fast(dr_c);
      float cand = tanh_fast(cx_c + hdot);
      float hn = (1.f - dlt) * h_own + dlt * cand;
      // critical path first: publish tagged h to the other blocks
      uint16_t hb16 = __builtin_bit_cast(uint16_t, (f16)hn);
      __hip_atomic_store(&slot[e], (want << 16) | (uint32_t)hb16,
                         __ATOMIC_RELAXED, __HIP_MEMORY_SCOPE_AGENT);
      size_t base = (size_t)t * 16384 + (size_t)batch * DD + e;
      float z = hn + xv_c + bgv;
      d_out[base] = hn * z * sigmoid_fast(z);          // out[t]  (overwrites consumed cand_x[t])
      d_out[H0OFF + 16384 + base] = hn;                // h[t+1]  (overwrites consumed delta_raw[t])
      h_own = hn; cx_c = cx_n; dr_c = dr_n; xv_c = xv_n;
    }

    if (t + 1 < TT) {
      // all 256 threads poll their 4 tagged words (the poll IS the data load)
      uint32_t* wp = slot + 4 * tid;
      uint32_t w0, w1, w2, w3;
      while (true) {
        w0 = __hip_atomic_load(wp + 0, __ATOMIC_RELAXED, __HIP_MEMORY_SCOPE_AGENT);
        w1 = __hip_atomic_load(wp + 1, __ATOMIC_RELAXED, __HIP_MEMORY_SCOPE_AGENT);
        w2 = __hip_atomic_load(wp + 2, __ATOMIC_RELAXED, __HIP_MEMORY_SCOPE_AGENT);
        w3 = __hip_atomic_load(wp + 3, __ATOMIC_RELAXED, __HIP_MEMORY_SCOPE_AGENT);
        if (((w0 >> 16) == want) && ((w1 >> 16) == want) &&
            ((w2 >> 16) == want) && ((w3 >> 16) == want)) break;
      }
      hsh[2 * tid]     = (w0 & 0xffffu) | (w1 << 16);
      hsh[2 * tid + 1] = (w2 & 0xffffu) | (w3 << 16);
      __syncthreads();                                // barrier B
    }
  }
}

// ---------------- launch ----------------
extern "C" void kernel_launch(void* const* d_in, const int* in_sizes, int n_in,
                              void* d_out_v, int out_size, void* d_ws, size_t ws_size,
                              hipStream_t stream) {
  const float* x  = (const float*)d_in[0];
  const float* h0 = (const float*)d_in[1];
  const float* Wx = (const float*)d_in[2];
  const float* Wh = (const float*)d_in[3];
  const float* Wd = (const float*)d_in[4];
  const float* b  = (const float*)d_in[5];
  const float* bd = (const float*)d_in[6];
  const float* bg = (const float*)d_in[7];
  float* out = (float*)d_out_v;

  char* ws = (char*)d_ws;
  float* u    = (float*)(ws + 0);
  float* v    = (float*)(ws + 4096);
  float* t0   = (float*)(ws + 8192);
  float* sc   = (float*)(ws + 12288);
  uint32_t* hx = (uint32_t*)(ws + 65536);        // 16 slots * 16 batches * 1024 words = 1 MiB
  f16* WhH  = (f16*)(ws + 2097152);              // 2 MiB

  hipMemsetAsync(hx, 0, (size_t)16 * BB * DD * 4, stream);  // clear ring tags (replay safety)

  k_u0<<<1, 512, 0, stream>>>(t0, u);
  for (int it = 0; it < 3; ++it) {
    k_mvT<<<4, 256, 0, stream>>>(Wh, u, t0);
    k_norm<<<1, 1024, 0, stream>>>(t0, v, 1e-8f);
    k_mv<<<16, 256, 0, stream>>>(Wh, v, t0);
    k_norm<<<1, 1024, 0, stream>>>(t0, u, 1e-8f);
  }
  k_sigma<<<1, 1024, 0, stream>>>(u, t0, sc);
  k_castWh<<<4096, 256, 0, stream>>>(Wh, sc, WhH);

  dim3 gg(256, 8, 1);
  k_gemm<<<gg, 256, 0, stream>>>(x, Wx, b, out);                   // cand_x -> out region
  k_gemm<<<gg, 256, 0, stream>>>(x, Wd, bd, out + H0OFF + 16384);  // delta_raw -> h region (+1 slot)

  k_rec<<<256, 256, 0, stream>>>(x, h0, bg, WhH, hx, out);
}